// Round 4
// baseline (225.282 us; speedup 1.0000x reference)
//
#include <hip/hip_runtime.h>
#include <hip/hip_bf16.h>
#include <hip/hip_cooperative_groups.h>
#include <math.h>

namespace cg = cooperative_groups;

// ---------------------------------------------------------------------------
// Primary: ONE cooperative kernel, 4 phases separated by grid.sync(), every
// phase grid-stride so ANY grid size is correct. Grid chosen from a host-side
// occupancy query; launch return code checked.
// Fallback: the proven 4-kernel pipeline (round 2, 77 us) if coop unavailable.
// ---------------------------------------------------------------------------

#define B 2
#define N 1024          // 32x32 patches
#define HW 512
#define IMG (HW*HW)
#define NTHR 256
#define MAXBLK 1024

// ---- one wave computes one query of 1024-token, d=8 attention -------------
__device__ __forceinline__ void attn_wave(const float* __restrict__ Qp,
                                          const float* __restrict__ Kb,
                                          const float* __restrict__ Vb,
                                          int lane, float f[8]) {
    const float4 q0 = ((const float4*)Qp)[0];
    const float4 q1 = ((const float4*)Qp)[1];
    float dots[16];
    float mx = -3.0e38f;
#pragma unroll
    for (int t = 0; t < 16; ++t) {
        const float4* kr = (const float4*)(Kb + (t * 64 + lane) * 8);
        const float4 k0 = kr[0], k1 = kr[1];
        float d = q0.x * k0.x;
        d = fmaf(q0.y, k0.y, d); d = fmaf(q0.z, k0.z, d); d = fmaf(q0.w, k0.w, d);
        d = fmaf(q1.x, k1.x, d); d = fmaf(q1.y, k1.y, d);
        d = fmaf(q1.z, k1.z, d); d = fmaf(q1.w, k1.w, d);
        d *= 0.35355339059327373f;     // 8^-0.5
        dots[t] = d;
        mx = fmaxf(mx, d);
    }
#pragma unroll
    for (int off = 1; off < 64; off <<= 1) mx = fmaxf(mx, __shfl_xor(mx, off));
    float s = 0.f;
    float va[8] = {0.f, 0.f, 0.f, 0.f, 0.f, 0.f, 0.f, 0.f};
#pragma unroll
    for (int t = 0; t < 16; ++t) {
        const float e = exp2f((dots[t] - mx) * 1.4426950408889634f);
        s += e;
        const float4* vr = (const float4*)(Vb + (t * 64 + lane) * 8);
        const float4 v0 = vr[0], v1 = vr[1];
        va[0] = fmaf(e, v0.x, va[0]); va[1] = fmaf(e, v0.y, va[1]);
        va[2] = fmaf(e, v0.z, va[2]); va[3] = fmaf(e, v0.w, va[3]);
        va[4] = fmaf(e, v1.x, va[4]); va[5] = fmaf(e, v1.y, va[5]);
        va[6] = fmaf(e, v1.z, va[6]); va[7] = fmaf(e, v1.w, va[7]);
    }
#pragma unroll
    for (int off = 1; off < 64; off <<= 1) {
        s += __shfl_xor(s, off);
#pragma unroll
        for (int d2 = 0; d2 < 8; ++d2) va[d2] += __shfl_xor(va[d2], off);
    }
    const float inv = 1.f / s;
#pragma unroll
    for (int d2 = 0; d2 < 8; ++d2) f[d2] = va[d2] * inv;
}

// ---- bilateral filter, compile-time k -------------------------------------
template<int KK>
__device__ __forceinline__ void filt_spec(const float* __restrict__ xb, int h, int w,
                                          float nix, float niy, float nir,
                                          bool interiorBlk, float* __restrict__ out, int id) {
    constexpr int P = KK / 2;
    float ex[KK];
#pragma unroll
    for (int j = 0; j < KK; ++j) ex[j] = (float)((j - P) * (j - P)) * nix;
    const float xc = xb[h * HW + w];
    float acc0 = 0.f, ws0 = 0.f, acc1 = 0.f, ws1 = 0.f;
    if (interiorBlk) {
        const float* base = xb + (h - P) * HW + (w - P);
#pragma unroll
        for (int i = 0; i < KK; ++i) {
            const float eyr = (float)((i - P) * (i - P)) * niy;
            const float* row = base + i * HW;
#pragma unroll
            for (int j = 0; j < KK; ++j) {
                const float xv = row[j];
                const float dd = xc - xv;
                const float wg = exp2f(fmaf(dd * dd, nir, eyr + ex[j]));
                if (j & 1) { ws1 += wg; acc1 = fmaf(wg, xv, acc1); }
                else       { ws0 += wg; acc0 = fmaf(wg, xv, acc0); }
            }
        }
    } else {
#pragma unroll
        for (int i = 0; i < KK; ++i) {
            int row = h + i - P;
            row = (row < 0) ? -row : ((row > HW - 1) ? 2 * HW - 2 - row : row);
            const float eyr = (float)((i - P) * (i - P)) * niy;
            const float* rp = xb + row * HW;
#pragma unroll
            for (int j = 0; j < KK; ++j) {
                int col = w + j - P;
                col = (col < 0) ? -col : ((col > HW - 1) ? 2 * HW - 2 - col : col);
                const float xv = rp[col];
                const float dd = xc - xv;
                const float wg = exp2f(fmaf(dd * dd, nir, eyr + ex[j]));
                if (j & 1) { ws1 += wg; acc1 = fmaf(wg, xv, acc1); }
                else       { ws0 += wg; acc0 = fmaf(wg, xv, acc0); }
            }
        }
    }
    out[id] = (acc0 + acc1) / (ws0 + ws1 + 1e-8f);
}

__device__ void filt_generic(const float* __restrict__ xb, int h, int w, int kk,
                             float nix, float niy, float nir,
                             float* __restrict__ out, int id) {
    const int P = kk >> 1;
    const float xc = xb[h * HW + w];
    float acc = 0.f, wsum = 0.f;
    for (int i = 0; i < kk; ++i) {
        int row = h + i - P;
        row = (row < 0) ? -row : ((row > HW - 1) ? 2 * HW - 2 - row : row);
        const float eyr = (float)((i - P) * (i - P)) * niy;
        const float* rp = xb + row * HW;
        for (int j = 0; j < kk; ++j) {
            int col = w + j - P;
            col = (col < 0) ? -col : ((col > HW - 1) ? 2 * HW - 2 - col : col);
            const float xv = rp[col];
            const float dd = xc - xv;
            const float wg = exp2f(fmaf(dd * dd, nir, eyr + (float)((j - P) * (j - P)) * nix));
            wsum += wg;
            acc = fmaf(wg, xv, acc);
        }
    }
    out[id] = acc / (wsum + 1e-8f);
}

// ---- device helpers shared by phases ---------------------------------------
__device__ __forceinline__ void qkv_body(const float* __restrict__ x,
                                         const float* __restrict__ Wq, const float* __restrict__ bq,
                                         const float* __restrict__ Wk, const float* __restrict__ bk,
                                         const float* __restrict__ Wv, const float* __restrict__ bv,
                                         float* __restrict__ Q, float* __restrict__ K, float* __restrict__ V,
                                         float* __restrict__ p, int bn, int tid) {
    const int b = bn >> 10, n = bn & 1023;
    const int ph = n >> 5, pw = n & 31;
    p[tid] = x[b * IMG + (ph * 16 + (tid >> 4)) * HW + pw * 16 + (tid & 15)];
    __syncthreads();
    if (tid < 192) {
        const int o = tid >> 3, sub = tid & 7;   // 24 outputs x 8 partials
        const int mat = o >> 3, j = o & 7;       // wave-uniform mat
        const float* W  = (mat == 0) ? Wq : (mat == 1) ? Wk : Wv;
        const float* bb = (mat == 0) ? bq : (mat == 1) ? bk : bv;
        float sum = 0.f;
#pragma unroll
        for (int dd = 0; dd < 32; ++dd) {
            const int d = dd * 8 + sub;
            sum = fmaf(p[d], W[d * 8 + j], sum);
        }
        sum += __shfl_xor(sum, 1);
        sum += __shfl_xor(sum, 2);
        sum += __shfl_xor(sum, 4);
        if (sub == 0) {
            float* op = (mat == 0) ? Q : (mat == 1) ? K : V;
            op[bn * 8 + j] = sum + bb[j];
        }
    }
    __syncthreads();
}

__device__ __forceinline__ void attn_proj_body(const float* __restrict__ Q,
                                               const float* __restrict__ K, const float* __restrict__ V,
                                               const float* __restrict__ Wsq, const float* __restrict__ bsq,
                                               const float* __restrict__ Wsk, const float* __restrict__ bsk,
                                               const float* __restrict__ Wsv, const float* __restrict__ bsv,
                                               float* __restrict__ SQ, float* __restrict__ SK,
                                               float* __restrict__ SV, int bn, int lane) {
    const int b = bn >> 10;
    float f[8];
    attn_wave(Q + bn * 8, K + (b << 13), V + (b << 13), lane, f);
    if (lane < 24) {
        const int mat = lane >> 3, j = lane & 7;
        const float* W  = (mat == 0) ? Wsq : (mat == 1) ? Wsk : Wsv;
        const float* bb = (mat == 0) ? bsq : (mat == 1) ? bsk : bsv;
        float o = bb[j];
#pragma unroll
        for (int d = 0; d < 8; ++d) o = fmaf(f[d], W[d * 8 + j], o);
        float* op = (mat == 0) ? SQ : (mat == 1) ? SK : SV;
        op[bn * 8 + j] = o;
    }
}

__device__ __forceinline__ void attn_head_body(const float* __restrict__ SQ,
                                               const float* __restrict__ SK, const float* __restrict__ SV,
                                               const float* __restrict__ g, const float* __restrict__ be,
                                               const float* __restrict__ Wp, const float* __restrict__ bp,
                                               float* __restrict__ SP, unsigned int* __restrict__ maxbits,
                                               int bn, int lane) {
    const int b = bn >> 10;
    float f[8];
    attn_wave(SQ + bn * 8, SK + (b << 13), SV + (b << 13), lane, f);
    float mu = 0.f;
#pragma unroll
    for (int d = 0; d < 8; ++d) mu += f[d];
    mu *= 0.125f;
    float var = 0.f;
#pragma unroll
    for (int d = 0; d < 8; ++d) { const float t = f[d] - mu; var = fmaf(t, t, var); }
    var *= 0.125f;
    const float inv = rsqrtf(var + 1e-5f);
    float val = 0.f;
    if (lane < 3) {
        float o = bp[lane];
#pragma unroll
        for (int d = 0; d < 8; ++d) {
            const float nrm = (f[d] - mu) * inv * g[d] + be[d];
            o = fmaf(nrm, Wp[d * 3 + lane], o);
        }
        const float sp = fmaxf(o, 0.f) + log1pf(__expf(-fabsf(o)));
        const float v = fminf(sp, 6.0f) + 1e-6f;
        SP[bn * 3 + lane] = v;
        val = (lane < 2) ? v : 0.f;   // only sx, sy feed kernel size
    }
    float mv = val;
#pragma unroll
    for (int off = 1; off < 64; off <<= 1) mv = fmaxf(mv, __shfl_xor(mv, off));
    if (lane == 0) atomicMax(maxbits, __float_as_uint(mv));
}

__device__ __forceinline__ void filter_body(const float* __restrict__ x,
                                            const float* __restrict__ SP,
                                            float* __restrict__ out, int bn, int tid, int kk) {
    constexpr float L2E = 1.4426950408889634f;
    const int b = bn >> 10, n = bn & 1023;
    const int ph = n >> 5, pw = n & 31;
    const int h = ph * 16 + (tid >> 4), w = pw * 16 + (tid & 15);
    const int id = b * IMG + h * HW + w;
    const float* xb = x + b * IMG;
    const float* sp = SP + bn * 3;
    const float sx = sp[0], sy = sp[1], sr = sp[2];
    const float nix = -0.5f * L2E / (sx * sx);
    const float niy = -0.5f * L2E / (sy * sy);
    const float nir = -0.5f * L2E / (sr * sr);
    const bool ib = (ph > 0) & (ph < 31) & (pw > 0) & (pw < 31);
    if (kk == 11)      filt_spec<11>(xb, h, w, nix, niy, nir, ib, out, id);
    else if (kk == 9)  filt_spec<9>(xb, h, w, nix, niy, nir, ib, out, id);
    else if (kk == 13) filt_spec<13>(xb, h, w, nix, niy, nir, ib, out, id);
    else               filt_generic(xb, h, w, kk, nix, niy, nir, out, id);
}

// ======================= PRIMARY: cooperative fused =========================
__global__ __launch_bounds__(NTHR, 4)
void fused_kernel(const float* __restrict__ x,
                  const float* __restrict__ Wq, const float* __restrict__ bq,
                  const float* __restrict__ Wk, const float* __restrict__ bk,
                  const float* __restrict__ Wv, const float* __restrict__ bv,
                  const float* __restrict__ Wsq, const float* __restrict__ bsq,
                  const float* __restrict__ Wsk, const float* __restrict__ bsk,
                  const float* __restrict__ Wsv, const float* __restrict__ bsv,
                  const float* __restrict__ g, const float* __restrict__ be,
                  const float* __restrict__ Wp, const float* __restrict__ bp,
                  float* __restrict__ ws, float* __restrict__ out) {
    float* Q  = ws;
    float* K  = ws + 16384;
    float* V  = ws + 32768;
    float* SQ = ws + 49152;
    float* SK = ws + 65536;
    float* SV = ws + 81920;
    float* SP = ws + 98304;
    unsigned int* maxbits = (unsigned int*)(ws + 104448);

    const int bid = blockIdx.x, tid = threadIdx.x;
    const int nb = gridDim.x;
    const int wid = tid >> 6, lane = tid & 63;
    __shared__ float p[256];

    // ---- phase 1: patchify + QKV (grid-stride over patches) ----
    if (bid == 0 && tid == 0) atomicExch(maxbits, 0u);
    for (int bn = bid; bn < B * N; bn += nb)
        qkv_body(x, Wq, bq, Wk, bk, Wv, bv, Q, K, V, p, bn, tid);
    cg::this_grid().sync();

    // ---- phase 2: attention #1 + stage-2 projection (1 wave/query) ----
    for (int bn = bid * 4 + wid; bn < B * N; bn += nb * 4)
        attn_proj_body(Q, K, V, Wsq, bsq, Wsk, bsk, Wsv, bsv, SQ, SK, SV, bn, lane);
    cg::this_grid().sync();

    // ---- phase 3: attention #2 + LN + sigma head + global max ----
    for (int bn = bid * 4 + wid; bn < B * N; bn += nb * 4)
        attn_head_body(SQ, SK, SV, g, be, Wp, bp, SP, maxbits, bn, lane);
    cg::this_grid().sync();

    // ---- phase 4: bilateral filter ----
    const float m = __uint_as_float(
        __hip_atomic_load(maxbits, __ATOMIC_RELAXED, __HIP_MEMORY_SCOPE_AGENT));
    int kk = 2 * (int)ceilf(m) + 1;
    if (kk < 1) kk = 1;
    if (kk > 31) kk = 31;
    for (int bn = bid; bn < B * N; bn += nb)
        filter_body(x, SP, out, bn, tid, kk);
}

// ======================= FALLBACK: 4-kernel pipeline ========================
__global__ __launch_bounds__(256)
void qkv_kernel(const float* __restrict__ x,
                const float* __restrict__ Wq, const float* __restrict__ bq,
                const float* __restrict__ Wk, const float* __restrict__ bk,
                const float* __restrict__ Wv, const float* __restrict__ bv,
                float* __restrict__ Q, float* __restrict__ K, float* __restrict__ V,
                unsigned int* __restrict__ maxbits) {
    const int bn = blockIdx.x, tid = threadIdx.x;
    if (bn == 0 && tid == 0) atomicExch(maxbits, 0u);
    __shared__ float p[256];
    qkv_body(x, Wq, bq, Wk, bk, Wv, bv, Q, K, V, p, bn, tid);
}

__global__ __launch_bounds__(256)
void attn_proj_kernel(const float* __restrict__ Q, const float* __restrict__ K,
                      const float* __restrict__ V,
                      const float* __restrict__ Wsq, const float* __restrict__ bsq,
                      const float* __restrict__ Wsk, const float* __restrict__ bsk,
                      const float* __restrict__ Wsv, const float* __restrict__ bsv,
                      float* __restrict__ SQ, float* __restrict__ SK, float* __restrict__ SV) {
    const int wid = threadIdx.x >> 6, lane = threadIdx.x & 63;
    const int bn = blockIdx.x * 4 + wid;
    if (bn < B * N)
        attn_proj_body(Q, K, V, Wsq, bsq, Wsk, bsk, Wsv, bsv, SQ, SK, SV, bn, lane);
}

__global__ __launch_bounds__(256)
void attn_head_kernel(const float* __restrict__ SQ, const float* __restrict__ SK,
                      const float* __restrict__ SV,
                      const float* __restrict__ g, const float* __restrict__ be,
                      const float* __restrict__ Wp, const float* __restrict__ bp,
                      float* __restrict__ SP, unsigned int* __restrict__ maxbits) {
    const int wid = threadIdx.x >> 6, lane = threadIdx.x & 63;
    const int bn = blockIdx.x * 4 + wid;
    if (bn < B * N)
        attn_head_body(SQ, SK, SV, g, be, Wp, bp, SP, maxbits, bn, lane);
}

__global__ __launch_bounds__(256)
void filter_kernel(const float* __restrict__ x, const float* __restrict__ SP,
                   const unsigned int* __restrict__ maxbits, float* __restrict__ out) {
    const float m = __uint_as_float(*maxbits);
    int kk = 2 * (int)ceilf(m) + 1;
    if (kk < 1) kk = 1;
    if (kk > 31) kk = 31;
    filter_body(x, SP, out, blockIdx.x, threadIdx.x, kk);
}

extern "C" void kernel_launch(void* const* d_in, const int* in_sizes, int n_in,
                              void* d_out, int out_size, void* d_ws, size_t ws_size,
                              hipStream_t stream) {
    const float* x    = (const float*)d_in[0];
    const float* Wq   = (const float*)d_in[1];
    const float* bq   = (const float*)d_in[2];
    const float* Wk   = (const float*)d_in[3];
    const float* bk   = (const float*)d_in[4];
    const float* Wv   = (const float*)d_in[5];
    const float* bv   = (const float*)d_in[6];
    const float* Wsq  = (const float*)d_in[7];
    const float* bsq  = (const float*)d_in[8];
    const float* Wsk  = (const float*)d_in[9];
    const float* bsk  = (const float*)d_in[10];
    const float* Wsv  = (const float*)d_in[11];
    const float* bsv  = (const float*)d_in[12];
    const float* ln_g = (const float*)d_in[13];
    const float* ln_b = (const float*)d_in[14];
    const float* Wp   = (const float*)d_in[15];
    const float* bp   = (const float*)d_in[16];
    float* ws  = (float*)d_ws;
    float* out = (float*)d_out;

    float* Q   = ws;
    float* Kf  = ws + 16384;
    float* Vf  = ws + 32768;
    float* SQ  = ws + 49152;
    float* SK  = ws + 65536;
    float* SV  = ws + 81920;
    float* SP  = ws + 98304;
    unsigned int* maxbits = (unsigned int*)(ws + 104448);

    // ---- host-side capability check (capture-safe: no stream interaction) ----
    int dev = 0;
    (void)hipGetDevice(&dev);
    int coopSupported = 0;
    (void)hipDeviceGetAttribute(&coopSupported, hipDeviceAttributeCooperativeLaunch, dev);
    int numCU = 0;
    (void)hipDeviceGetAttribute(&numCU, hipDeviceAttributeMultiprocessorCount, dev);
    int perCU = 0;
    hipError_t oerr = hipOccupancyMaxActiveBlocksPerMultiprocessor(
        &perCU, (const void*)fused_kernel, NTHR, 0);
    long cap = (oerr == hipSuccess) ? (long)perCU * (long)numCU : 0;

    if (coopSupported && cap >= 64) {
        int grid = (int)(cap < MAXBLK ? cap : MAXBLK);
        void* args[] = {
            (void*)&x,
            (void*)&Wq, (void*)&bq, (void*)&Wk, (void*)&bk, (void*)&Wv, (void*)&bv,
            (void*)&Wsq, (void*)&bsq, (void*)&Wsk, (void*)&bsk, (void*)&Wsv, (void*)&bsv,
            (void*)&ln_g, (void*)&ln_b, (void*)&Wp, (void*)&bp,
            (void*)&ws, (void*)&out
        };
        hipError_t lerr = hipLaunchCooperativeKernel((void*)fused_kernel, dim3(grid),
                                                     dim3(NTHR), args, 0, stream);
        if (lerr == hipSuccess) return;
    }

    // ---- fallback: proven 4-kernel pipeline ----
    qkv_kernel<<<B * N, 256, 0, stream>>>(x, Wq, bq, Wk, bk, Wv, bv, Q, Kf, Vf, maxbits);
    attn_proj_kernel<<<B * N / 4, 256, 0, stream>>>(Q, Kf, Vf, Wsq, bsq, Wsk, bsk, Wsv, bsv, SQ, SK, SV);
    attn_head_kernel<<<B * N / 4, 256, 0, stream>>>(SQ, SK, SV, ln_g, ln_b, Wp, bp, SP, maxbits);
    filter_kernel<<<B * N, 256, 0, stream>>>(x, SP, maxbits, out);
}

// Round 5
// 81.601 us; speedup vs baseline: 2.7608x; 2.7608x over previous
//
#include <hip/hip_runtime.h>
#include <hip/hip_bf16.h>
#include <math.h>

// ---------------------------------------------------------------------------
// 4-kernel pipeline (round-2 structure, proven correct at 77us), with the
// bilateral filter rewritten to stage its patch window in LDS:
//  K1 qkv_kernel    : patchify + 3x linear (256->8), zeroes maxbits   [2048 blk]
//  K2 attn_proj     : attention #1 (wave/query) + fused 3x(8->8) proj [512 blk]
//  K3 attn_head     : attention #2 + fused LN + head + bsp + atomicMax
//  K4 filter_kernel : bilateral filter, LDS-staged window, k specialized
// NOTE: no cooperative launch — grid.sync() measured ~100us/sync on MI355X
// (round 4: 3 syncs -> 380us dispatch). Multi-kernel is strictly better here.
// ---------------------------------------------------------------------------

#define B 2
#define N 1024          // 32x32 patches
#define HW 512
#define IMG (HW*HW)

// ---- one wave computes one query of 1024-token, d=8 attention -------------
__device__ __forceinline__ void attn_wave(const float* __restrict__ Qp,
                                          const float* __restrict__ Kb,
                                          const float* __restrict__ Vb,
                                          int lane, float f[8]) {
    const float4 q0 = ((const float4*)Qp)[0];
    const float4 q1 = ((const float4*)Qp)[1];
    float dots[16];
    float mx = -3.0e38f;
#pragma unroll
    for (int t = 0; t < 16; ++t) {
        const float4* kr = (const float4*)(Kb + (t * 64 + lane) * 8);
        const float4 k0 = kr[0], k1 = kr[1];
        float d = q0.x * k0.x;
        d = fmaf(q0.y, k0.y, d); d = fmaf(q0.z, k0.z, d); d = fmaf(q0.w, k0.w, d);
        d = fmaf(q1.x, k1.x, d); d = fmaf(q1.y, k1.y, d);
        d = fmaf(q1.z, k1.z, d); d = fmaf(q1.w, k1.w, d);
        d *= 0.35355339059327373f;     // 8^-0.5
        dots[t] = d;
        mx = fmaxf(mx, d);
    }
#pragma unroll
    for (int off = 1; off < 64; off <<= 1) mx = fmaxf(mx, __shfl_xor(mx, off));
    float s = 0.f;
    float va[8] = {0.f, 0.f, 0.f, 0.f, 0.f, 0.f, 0.f, 0.f};
#pragma unroll
    for (int t = 0; t < 16; ++t) {
        const float e = exp2f((dots[t] - mx) * 1.4426950408889634f);
        s += e;
        const float4* vr = (const float4*)(Vb + (t * 64 + lane) * 8);
        const float4 v0 = vr[0], v1 = vr[1];
        va[0] = fmaf(e, v0.x, va[0]); va[1] = fmaf(e, v0.y, va[1]);
        va[2] = fmaf(e, v0.z, va[2]); va[3] = fmaf(e, v0.w, va[3]);
        va[4] = fmaf(e, v1.x, va[4]); va[5] = fmaf(e, v1.y, va[5]);
        va[6] = fmaf(e, v1.z, va[6]); va[7] = fmaf(e, v1.w, va[7]);
    }
#pragma unroll
    for (int off = 1; off < 64; off <<= 1) {
        s += __shfl_xor(s, off);
#pragma unroll
        for (int d2 = 0; d2 < 8; ++d2) va[d2] += __shfl_xor(va[d2], off);
    }
    const float inv = 1.f / s;
#pragma unroll
    for (int d2 = 0; d2 < 8; ++d2) f[d2] = va[d2] * inv;
}

// ---- K1: patchify + QKV projection ---------------------------------------
__global__ __launch_bounds__(256)
void qkv_kernel(const float* __restrict__ x,
                const float* __restrict__ Wq, const float* __restrict__ bq,
                const float* __restrict__ Wk, const float* __restrict__ bk,
                const float* __restrict__ Wv, const float* __restrict__ bv,
                float* __restrict__ Q, float* __restrict__ K, float* __restrict__ V,
                unsigned int* __restrict__ maxbits) {
    const int bn = blockIdx.x;
    const int b  = bn >> 10, n = bn & 1023;
    const int ph = n >> 5, pw = n & 31;
    const int tid = threadIdx.x;
    if (bn == 0 && tid == 0) atomicExch(maxbits, 0u);   // fresh every call
    __shared__ float p[256];
    p[tid] = x[b * IMG + (ph * 16 + (tid >> 4)) * HW + pw * 16 + (tid & 15)];
    __syncthreads();
    if (tid < 192) {
        const int o = tid >> 3, sub = tid & 7;   // 24 outputs x 8 partials
        const int mat = o >> 3, j = o & 7;       // wave-uniform mat
        const float* W  = (mat == 0) ? Wq : (mat == 1) ? Wk : Wv;
        const float* bb = (mat == 0) ? bq : (mat == 1) ? bk : bv;
        float sum = 0.f;
#pragma unroll
        for (int dd = 0; dd < 32; ++dd) {
            const int d = dd * 8 + sub;
            sum = fmaf(p[d], W[d * 8 + j], sum);
        }
        sum += __shfl_xor(sum, 1);
        sum += __shfl_xor(sum, 2);
        sum += __shfl_xor(sum, 4);
        if (sub == 0) {
            float* op = (mat == 0) ? Q : (mat == 1) ? K : V;
            op[bn * 8 + j] = sum + bb[j];
        }
    }
}

// ---- K2: attention #1 + fused second-stage QKV projection -----------------
__global__ __launch_bounds__(256)
void attn_proj_kernel(const float* __restrict__ Q, const float* __restrict__ K,
                      const float* __restrict__ V,
                      const float* __restrict__ Wsq, const float* __restrict__ bsq,
                      const float* __restrict__ Wsk, const float* __restrict__ bsk,
                      const float* __restrict__ Wsv, const float* __restrict__ bsv,
                      float* __restrict__ SQ, float* __restrict__ SK, float* __restrict__ SV) {
    const int wid = threadIdx.x >> 6, lane = threadIdx.x & 63;
    const int bn = blockIdx.x * 4 + wid, b = bn >> 10;
    float f[8];
    attn_wave(Q + bn * 8, K + (b << 13), V + (b << 13), lane, f);
    if (lane < 24) {
        const int mat = lane >> 3, j = lane & 7;
        const float* W  = (mat == 0) ? Wsq : (mat == 1) ? Wsk : Wsv;
        const float* bb = (mat == 0) ? bsq : (mat == 1) ? bsk : bsv;
        float o = bb[j];
#pragma unroll
        for (int d = 0; d < 8; ++d) o = fmaf(f[d], W[d * 8 + j], o);
        float* op = (mat == 0) ? SQ : (mat == 1) ? SK : SV;
        op[bn * 8 + j] = o;
    }
}

// ---- K3: attention #2 + fused LN + sigma head + global max ----------------
__global__ __launch_bounds__(256)
void attn_head_kernel(const float* __restrict__ SQ, const float* __restrict__ SK,
                      const float* __restrict__ SV,
                      const float* __restrict__ g, const float* __restrict__ be,
                      const float* __restrict__ Wp, const float* __restrict__ bp,
                      float* __restrict__ SP, unsigned int* __restrict__ maxbits) {
    const int wid = threadIdx.x >> 6, lane = threadIdx.x & 63;
    const int bn = blockIdx.x * 4 + wid, b = bn >> 10;
    float f[8];
    attn_wave(SQ + bn * 8, SK + (b << 13), SV + (b << 13), lane, f);
    float mu = 0.f;
#pragma unroll
    for (int d = 0; d < 8; ++d) mu += f[d];
    mu *= 0.125f;
    float var = 0.f;
#pragma unroll
    for (int d = 0; d < 8; ++d) { const float t = f[d] - mu; var = fmaf(t, t, var); }
    var *= 0.125f;
    const float inv = rsqrtf(var + 1e-5f);
    float val = 0.f;
    if (lane < 3) {
        float o = bp[lane];
#pragma unroll
        for (int d = 0; d < 8; ++d) {
            const float nrm = (f[d] - mu) * inv * g[d] + be[d];
            o = fmaf(nrm, Wp[d * 3 + lane], o);
        }
        const float sp = fmaxf(o, 0.f) + log1pf(__expf(-fabsf(o)));
        const float v = fminf(sp, 6.0f) + 1e-6f;
        SP[bn * 3 + lane] = v;
        val = (lane < 2) ? v : 0.f;    // only sx, sy feed the kernel-size max
    }
    float mv = val;
#pragma unroll
    for (int off = 1; off < 64; off <<= 1) mv = fmaxf(mv, __shfl_xor(mv, off));
    if (lane == 0) atomicMax(maxbits, __float_as_uint(mv));
}

// ---- K4: bilateral filter, LDS-staged window ------------------------------
// Window row stride 48 floats (== 16 mod 32 banks): every wave's LDS read is
// exactly 2-way bank-aliased, which is free on CDNA4 (m136).
#define WSTRIDE 48
#define WROWS   28          // supports P <= 6 (k <= 13)

template<int KK>
__device__ __forceinline__ void filt_spec_lds(const float* __restrict__ xb,
                                              int ph, int pw, int tid,
                                              float nix, float niy, float nir,
                                              float* __restrict__ out, int id,
                                              float* __restrict__ win) {
    constexpr int P = KK / 2, S = 16 + 2 * P;
    const int h0 = ph * 16, w0 = pw * 16;
    const bool ib = (ph > 0) & (ph < 31) & (pw > 0) & (pw < 31);
    if (ib) {
        const float* base = xb + (h0 - P) * HW + (w0 - P);
        for (int idx = tid; idx < S * S; idx += 256) {
            const int r = idx / S, c = idx - r * S;   // S compile-time: magic mul
            win[r * WSTRIDE + c] = base[r * HW + c];
        }
    } else {
        for (int idx = tid; idx < S * S; idx += 256) {
            const int r = idx / S, c = idx - r * S;
            int gr = h0 - P + r; gr = (gr < 0) ? -gr : ((gr > HW - 1) ? 2 * HW - 2 - gr : gr);
            int gc = w0 - P + c; gc = (gc < 0) ? -gc : ((gc > HW - 1) ? 2 * HW - 2 - gc : gc);
            win[r * WSTRIDE + c] = xb[gr * HW + gc];
        }
    }
    __syncthreads();
    const int lr = tid >> 4, lc = tid & 15;
    float ex[KK];
#pragma unroll
    for (int j = 0; j < KK; ++j) ex[j] = (float)((j - P) * (j - P)) * nix;
    const float xc = win[(lr + P) * WSTRIDE + lc + P];
    float acc0 = 0.f, ws0 = 0.f, acc1 = 0.f, ws1 = 0.f;
#pragma unroll
    for (int i = 0; i < KK; ++i) {
        const float eyr = (float)((i - P) * (i - P)) * niy;
        const float* row = win + (lr + i) * WSTRIDE + lc;
#pragma unroll
        for (int j = 0; j < KK; ++j) {
            const float xv = row[j];
            const float dd = xc - xv;
            const float wg = exp2f(fmaf(dd * dd, nir, eyr + ex[j]));
            if (j & 1) { ws1 += wg; acc1 = fmaf(wg, xv, acc1); }
            else       { ws0 += wg; acc0 = fmaf(wg, xv, acc0); }
        }
    }
    out[id] = (acc0 + acc1) / (ws0 + ws1 + 1e-8f);
}

__device__ void filt_generic(const float* __restrict__ xb, int h, int w, int kk,
                             float nix, float niy, float nir,
                             float* __restrict__ out, int id) {
    const int P = kk >> 1;
    const float xc = xb[h * HW + w];
    float acc = 0.f, wsum = 0.f;
    for (int i = 0; i < kk; ++i) {
        int row = h + i - P;
        row = (row < 0) ? -row : ((row > HW - 1) ? 2 * HW - 2 - row : row);
        const float eyr = (float)((i - P) * (i - P)) * niy;
        const float* rp = xb + row * HW;
        for (int j = 0; j < kk; ++j) {
            int col = w + j - P;
            col = (col < 0) ? -col : ((col > HW - 1) ? 2 * HW - 2 - col : col);
            const float xv = rp[col];
            const float dd = xc - xv;
            const float wg = exp2f(fmaf(dd * dd, nir, eyr + (float)((j - P) * (j - P)) * nix));
            wsum += wg;
            acc = fmaf(wg, xv, acc);
        }
    }
    out[id] = acc / (wsum + 1e-8f);
}

__global__ __launch_bounds__(256)
void filter_kernel(const float* __restrict__ x, const float* __restrict__ SP,
                   const unsigned int* __restrict__ maxbits, float* __restrict__ out) {
    __shared__ float win[WROWS * WSTRIDE];
    const int blk = blockIdx.x;
    const int b = blk >> 10, n = blk & 1023;
    const int ph = n >> 5, pw = n & 31;
    const int tid = threadIdx.x;
    const int h = ph * 16 + (tid >> 4), w = pw * 16 + (tid & 15);
    const int id = b * IMG + h * HW + w;
    const float* xb = x + b * IMG;
    const float* sp = SP + (b * N + n) * 3;
    const float sx = sp[0], sy = sp[1], sr = sp[2];
    constexpr float L2E = 1.4426950408889634f;
    const float nix = -0.5f * L2E / (sx * sx);
    const float niy = -0.5f * L2E / (sy * sy);
    const float nir = -0.5f * L2E / (sr * sr);
    const float m = __uint_as_float(*maxbits);
    int kk = 2 * (int)ceilf(m) + 1;                // always odd
    if (kk < 1) kk = 1;
    if (kk > 31) kk = 31;
    // kk is block-uniform (same global scalar) -> uniform branch, safe syncthreads
    if (kk == 11)      filt_spec_lds<11>(xb, ph, pw, tid, nix, niy, nir, out, id, win);
    else if (kk == 9)  filt_spec_lds<9>(xb, ph, pw, tid, nix, niy, nir, out, id, win);
    else if (kk == 13) filt_spec_lds<13>(xb, ph, pw, tid, nix, niy, nir, out, id, win);
    else if (kk == 7)  filt_spec_lds<7>(xb, ph, pw, tid, nix, niy, nir, out, id, win);
    else               filt_generic(xb, h, w, kk, nix, niy, nir, out, id);
}

extern "C" void kernel_launch(void* const* d_in, const int* in_sizes, int n_in,
                              void* d_out, int out_size, void* d_ws, size_t ws_size,
                              hipStream_t stream) {
    const float* x    = (const float*)d_in[0];
    const float* Wq   = (const float*)d_in[1];
    const float* bq   = (const float*)d_in[2];
    const float* Wk   = (const float*)d_in[3];
    const float* bk   = (const float*)d_in[4];
    const float* Wv   = (const float*)d_in[5];
    const float* bv   = (const float*)d_in[6];
    const float* Wsq  = (const float*)d_in[7];
    const float* bsq  = (const float*)d_in[8];
    const float* Wsk  = (const float*)d_in[9];
    const float* bsk  = (const float*)d_in[10];
    const float* Wsv  = (const float*)d_in[11];
    const float* bsv  = (const float*)d_in[12];
    const float* ln_g = (const float*)d_in[13];
    const float* ln_b = (const float*)d_in[14];
    const float* Wp   = (const float*)d_in[15];
    const float* bp   = (const float*)d_in[16];
    float* out = (float*)d_out;

    float* ws = (float*)d_ws;
    float* Q   = ws;                 // 16384 floats
    float* Kf  = ws + 16384;
    float* Vf  = ws + 32768;
    float* SQ  = ws + 49152;
    float* SK  = ws + 65536;
    float* SV  = ws + 81920;
    float* SP  = ws + 98304;         // 6144 floats
    unsigned int* maxbits = (unsigned int*)(ws + 104448);

    qkv_kernel<<<B * N, 256, 0, stream>>>(x, Wq, bq, Wk, bk, Wv, bv, Q, Kf, Vf, maxbits);
    attn_proj_kernel<<<B * N / 4, 256, 0, stream>>>(Q, Kf, Vf, Wsq, bsq, Wsk, bsk, Wsv, bsv, SQ, SK, SV);
    attn_head_kernel<<<B * N / 4, 256, 0, stream>>>(SQ, SK, SV, ln_g, ln_b, Wp, bp, SP, maxbits);
    filter_kernel<<<B * N, 256, 0, stream>>>(x, SP, maxbits, out);
}

// Round 6
// 66.181 us; speedup vs baseline: 3.4040x; 1.2330x over previous
//
#include <hip/hip_runtime.h>
#include <hip/hip_bf16.h>
#include <math.h>

// ---------------------------------------------------------------------------
// 4-kernel pipeline:
//  K1 qkv_kernel    : patchify + 3x linear (256->8), zeroes maxbits   [2048 blk]
//  K2 attn_proj     : attention #1, K/V staged in LDS (64KB/block),
//                     2 queries/wave + fused 3x(8->8) proj            [256 blk]
//  K3 attn_head     : attention #2 (same LDS scheme) + LN + head + atomicMax
//  K4 filter_kernel : bilateral filter, direct global loads, k specialized
// NOTE: no cooperative launch — grid.sync() measured ~100us/sync on MI355X.
// K/V staged in LDS because per-wave re-reading K/V from L2 was ~128MB of
// traffic per attention layer (~20us each at observed concurrency).
// ---------------------------------------------------------------------------

#define B 2
#define N 1024          // 32x32 patches
#define HW 512
#define IMG (HW*HW)

// ---- K1: patchify + QKV projection ---------------------------------------
__global__ __launch_bounds__(256)
void qkv_kernel(const float* __restrict__ x,
                const float* __restrict__ Wq, const float* __restrict__ bq,
                const float* __restrict__ Wk, const float* __restrict__ bk,
                const float* __restrict__ Wv, const float* __restrict__ bv,
                float* __restrict__ Q, float* __restrict__ K, float* __restrict__ V,
                unsigned int* __restrict__ maxbits) {
    const int bn = blockIdx.x;
    const int b  = bn >> 10, n = bn & 1023;
    const int ph = n >> 5, pw = n & 31;
    const int tid = threadIdx.x;
    if (bn == 0 && tid == 0) atomicExch(maxbits, 0u);   // fresh every call
    __shared__ float p[256];
    p[tid] = x[b * IMG + (ph * 16 + (tid >> 4)) * HW + pw * 16 + (tid & 15)];
    __syncthreads();
    if (tid < 192) {
        const int o = tid >> 3, sub = tid & 7;   // 24 outputs x 8 partials
        const int mat = o >> 3, j = o & 7;       // wave-uniform mat
        const float* W  = (mat == 0) ? Wq : (mat == 1) ? Wk : Wv;
        const float* bb = (mat == 0) ? bq : (mat == 1) ? bk : bv;
        float sum = 0.f;
#pragma unroll
        for (int dd = 0; dd < 32; ++dd) {
            const int d = dd * 8 + sub;
            sum = fmaf(p[d], W[d * 8 + j], sum);
        }
        sum += __shfl_xor(sum, 1);
        sum += __shfl_xor(sum, 2);
        sum += __shfl_xor(sum, 4);
        if (sub == 0) {
            float* op = (mat == 0) ? Q : (mat == 1) ? K : V;
            op[bn * 8 + j] = sum + bb[j];
        }
    }
}

// ---- shared LDS-staged attention core -------------------------------------
// Block: 256 threads, 8 queries (2 per wave). Kl/Vl transposed [d][token]
// (stride 1024 dwords: writes 2-way bank-aliased, reads 2-way — both free).
// Two-pass softmax; dots recomputed in pass 2 to save VGPRs.
__device__ __forceinline__ void attn_lds(const float* __restrict__ Qg,
                                         const float* __restrict__ Kb,
                                         const float* __restrict__ Vb,
                                         float* __restrict__ Kl, float* __restrict__ Vl,
                                         int qa, int qb, int tid, int lane,
                                         float fa[8], float fb[8]) {
    // stage K,V (8192 floats each) transposed into LDS
    for (int i = tid; i < 2048; i += 256) {
        const float4 kv = ((const float4*)Kb)[i];
        const int tok = i >> 1, d0 = (i & 1) * 4;
        Kl[(d0 + 0) * 1024 + tok] = kv.x;
        Kl[(d0 + 1) * 1024 + tok] = kv.y;
        Kl[(d0 + 2) * 1024 + tok] = kv.z;
        Kl[(d0 + 3) * 1024 + tok] = kv.w;
        const float4 vv = ((const float4*)Vb)[i];
        Vl[(d0 + 0) * 1024 + tok] = vv.x;
        Vl[(d0 + 1) * 1024 + tok] = vv.y;
        Vl[(d0 + 2) * 1024 + tok] = vv.z;
        Vl[(d0 + 3) * 1024 + tok] = vv.w;
    }
    __syncthreads();

    float qav[8], qbv[8];
#pragma unroll
    for (int d = 0; d < 8; ++d) { qav[d] = Qg[qa * 8 + d]; qbv[d] = Qg[qb * 8 + d]; }

    const float SC = 0.35355339059327373f;     // 8^-0.5
    const float L2E = 1.4426950408889634f;

    // pass 1: max over all 1024 keys
    float mxa = -3.0e38f, mxb = -3.0e38f;
#pragma unroll
    for (int t = 0; t < 16; ++t) {
        const int tok = t * 64 + lane;
        float da = 0.f, db = 0.f;
#pragma unroll
        for (int d = 0; d < 8; ++d) {
            const float kd = Kl[d * 1024 + tok];
            da = fmaf(qav[d], kd, da);
            db = fmaf(qbv[d], kd, db);
        }
        mxa = fmaxf(mxa, da); mxb = fmaxf(mxb, db);
    }
#pragma unroll
    for (int off = 1; off < 64; off <<= 1) {
        mxa = fmaxf(mxa, __shfl_xor(mxa, off));
        mxb = fmaxf(mxb, __shfl_xor(mxb, off));
    }
    mxa *= SC; mxb *= SC;

    // pass 2: exp-sum + weighted V
    float sa = 0.f, sb = 0.f;
    float va[8] = {0,0,0,0,0,0,0,0}, vb[8] = {0,0,0,0,0,0,0,0};
#pragma unroll
    for (int t = 0; t < 16; ++t) {
        const int tok = t * 64 + lane;
        float da = 0.f, db = 0.f;
#pragma unroll
        for (int d = 0; d < 8; ++d) {
            const float kd = Kl[d * 1024 + tok];
            da = fmaf(qav[d], kd, da);
            db = fmaf(qbv[d], kd, db);
        }
        const float ea = exp2f((da * SC - mxa) * L2E);
        const float eb = exp2f((db * SC - mxb) * L2E);
        sa += ea; sb += eb;
#pragma unroll
        for (int d = 0; d < 8; ++d) {
            const float vd = Vl[d * 1024 + tok];
            va[d] = fmaf(ea, vd, va[d]);
            vb[d] = fmaf(eb, vd, vb[d]);
        }
    }
#pragma unroll
    for (int off = 1; off < 64; off <<= 1) {
        sa += __shfl_xor(sa, off);
        sb += __shfl_xor(sb, off);
#pragma unroll
        for (int d = 0; d < 8; ++d) {
            va[d] += __shfl_xor(va[d], off);
            vb[d] += __shfl_xor(vb[d], off);
        }
    }
    const float ia = 1.f / sa, ib = 1.f / sb;
#pragma unroll
    for (int d = 0; d < 8; ++d) { fa[d] = va[d] * ia; fb[d] = vb[d] * ib; }
}

// ---- K2: attention #1 + fused second-stage QKV projection -----------------
__global__ __launch_bounds__(256)
void attn_proj_kernel(const float* __restrict__ Q, const float* __restrict__ K,
                      const float* __restrict__ V,
                      const float* __restrict__ Wsq, const float* __restrict__ bsq,
                      const float* __restrict__ Wsk, const float* __restrict__ bsk,
                      const float* __restrict__ Wsv, const float* __restrict__ bsv,
                      float* __restrict__ SQ, float* __restrict__ SK, float* __restrict__ SV) {
    __shared__ float Kl[8 * 1024];
    __shared__ float Vl[8 * 1024];
    const int tid = threadIdx.x, wid = tid >> 6, lane = tid & 63;
    const int q0 = blockIdx.x * 8;            // 8 queries per block, same batch
    const int b  = q0 >> 10;
    const int qa = q0 + wid * 2, qb = qa + 1;
    float fa[8], fb[8];
    attn_lds(Q, K + (b << 13), V + (b << 13), Kl, Vl, qa, qb, tid, lane, fa, fb);
    // proj: lanes 0-23 -> query a, lanes 32-55 -> query b
    const int sl = lane & 31;
    if (sl < 24) {
        const int mat = sl >> 3, j = sl & 7;
        const float* W  = (mat == 0) ? Wsq : (mat == 1) ? Wsk : Wsv;
        const float* bb = (mat == 0) ? bsq : (mat == 1) ? bsk : bsv;
        const float* f  = (lane < 32) ? fa : fb;
        const int bn    = (lane < 32) ? qa : qb;
        float o = bb[j];
#pragma unroll
        for (int d = 0; d < 8; ++d) o = fmaf(f[d], W[d * 8 + j], o);
        float* op = (mat == 0) ? SQ : (mat == 1) ? SK : SV;
        op[bn * 8 + j] = o;
    }
}

// ---- K3: attention #2 + fused LN + sigma head + global max ----------------
__global__ __launch_bounds__(256)
void attn_head_kernel(const float* __restrict__ SQ, const float* __restrict__ SK,
                      const float* __restrict__ SV,
                      const float* __restrict__ g, const float* __restrict__ be,
                      const float* __restrict__ Wp, const float* __restrict__ bp,
                      float* __restrict__ SP, unsigned int* __restrict__ maxbits) {
    __shared__ float Kl[8 * 1024];
    __shared__ float Vl[8 * 1024];
    const int tid = threadIdx.x, wid = tid >> 6, lane = tid & 63;
    const int q0 = blockIdx.x * 8;
    const int b  = q0 >> 10;
    const int qa = q0 + wid * 2, qb = qa + 1;
    float fa[8], fb[8];
    attn_lds(SQ, SK + (b << 13), SV + (b << 13), Kl, Vl, qa, qb, tid, lane, fa, fb);

    const float* f = (lane < 32) ? fa : fb;
    const int bn   = (lane < 32) ? qa : qb;
    float mu = 0.f;
#pragma unroll
    for (int d = 0; d < 8; ++d) mu += f[d];
    mu *= 0.125f;
    float var = 0.f;
#pragma unroll
    for (int d = 0; d < 8; ++d) { const float t = f[d] - mu; var = fmaf(t, t, var); }
    var *= 0.125f;
    const float inv = rsqrtf(var + 1e-5f);
    const int sl = lane & 31;
    float val = 0.f;
    if (sl < 3) {
        float o = bp[sl];
#pragma unroll
        for (int d = 0; d < 8; ++d) {
            const float nrm = (f[d] - mu) * inv * g[d] + be[d];
            o = fmaf(nrm, Wp[d * 3 + sl], o);
        }
        const float sp = fmaxf(o, 0.f) + log1pf(__expf(-fabsf(o)));
        const float v = fminf(sp, 6.0f) + 1e-6f;
        SP[bn * 3 + sl] = v;
        val = (sl < 2) ? v : 0.f;    // only sx, sy feed the kernel-size max
    }
    float mv = val;
#pragma unroll
    for (int off = 1; off < 64; off <<= 1) mv = fmaxf(mv, __shfl_xor(mv, off));
    if (lane == 0) atomicMax(maxbits, __float_as_uint(mv));
}

// ---- K4: bilateral filter (round-2 register version, proven fastest) ------
template<int KK>
__device__ __forceinline__ void filt_spec(const float* __restrict__ xb, int h, int w,
                                          float nix, float niy, float nir,
                                          bool interiorBlk, float* __restrict__ out, int id) {
    constexpr int P = KK / 2;
    float ex[KK];
#pragma unroll
    for (int j = 0; j < KK; ++j) ex[j] = (float)((j - P) * (j - P)) * nix;
    const float xc = xb[h * HW + w];
    float acc0 = 0.f, ws0 = 0.f, acc1 = 0.f, ws1 = 0.f;
    if (interiorBlk) {
        const float* base = xb + (h - P) * HW + (w - P);
#pragma unroll
        for (int i = 0; i < KK; ++i) {
            const float eyr = (float)((i - P) * (i - P)) * niy;
            const float* row = base + i * HW;
#pragma unroll
            for (int j = 0; j < KK; ++j) {
                const float xv = row[j];
                const float dd = xc - xv;
                const float wg = exp2f(fmaf(dd * dd, nir, eyr + ex[j]));
                if (j & 1) { ws1 += wg; acc1 = fmaf(wg, xv, acc1); }
                else       { ws0 += wg; acc0 = fmaf(wg, xv, acc0); }
            }
        }
    } else {
#pragma unroll
        for (int i = 0; i < KK; ++i) {
            int row = h + i - P;
            row = (row < 0) ? -row : ((row > HW - 1) ? 2 * HW - 2 - row : row);
            const float eyr = (float)((i - P) * (i - P)) * niy;
            const float* rp = xb + row * HW;
#pragma unroll
            for (int j = 0; j < KK; ++j) {
                int col = w + j - P;
                col = (col < 0) ? -col : ((col > HW - 1) ? 2 * HW - 2 - col : col);
                const float xv = rp[col];
                const float dd = xc - xv;
                const float wg = exp2f(fmaf(dd * dd, nir, eyr + ex[j]));
                if (j & 1) { ws1 += wg; acc1 = fmaf(wg, xv, acc1); }
                else       { ws0 += wg; acc0 = fmaf(wg, xv, acc0); }
            }
        }
    }
    out[id] = (acc0 + acc1) / (ws0 + ws1 + 1e-8f);
}

__device__ void filt_generic(const float* __restrict__ xb, int h, int w, int kk,
                             float nix, float niy, float nir,
                             float* __restrict__ out, int id) {
    const int P = kk >> 1;
    const float xc = xb[h * HW + w];
    float acc = 0.f, wsum = 0.f;
    for (int i = 0; i < kk; ++i) {
        int row = h + i - P;
        row = (row < 0) ? -row : ((row > HW - 1) ? 2 * HW - 2 - row : row);
        const float eyr = (float)((i - P) * (i - P)) * niy;
        const float* rp = xb + row * HW;
        for (int j = 0; j < kk; ++j) {
            int col = w + j - P;
            col = (col < 0) ? -col : ((col > HW - 1) ? 2 * HW - 2 - col : col);
            const float xv = rp[col];
            const float dd = xc - xv;
            const float wg = exp2f(fmaf(dd * dd, nir, eyr + (float)((j - P) * (j - P)) * nix));
            wsum += wg;
            acc = fmaf(wg, xv, acc);
        }
    }
    out[id] = acc / (wsum + 1e-8f);
}

__global__ __launch_bounds__(256)
void filter_kernel(const float* __restrict__ x, const float* __restrict__ SP,
                   const unsigned int* __restrict__ maxbits, float* __restrict__ out) {
    const int blk = blockIdx.x;
    const int b = blk >> 10, n = blk & 1023;
    const int ph = n >> 5, pw = n & 31;
    const int tid = threadIdx.x;
    const int h = ph * 16 + (tid >> 4), w = pw * 16 + (tid & 15);
    const int id = b * IMG + h * HW + w;
    const float* xb = x + b * IMG;
    const float* sp = SP + (b * N + n) * 3;
    const float sx = sp[0], sy = sp[1], sr = sp[2];
    constexpr float L2E = 1.4426950408889634f;
    const float nix = -0.5f * L2E / (sx * sx);
    const float niy = -0.5f * L2E / (sy * sy);
    const float nir = -0.5f * L2E / (sr * sr);
    const float m = __uint_as_float(*maxbits);
    int kk = 2 * (int)ceilf(m) + 1;                // always odd
    if (kk < 1) kk = 1;
    if (kk > 31) kk = 31;
    const bool ib = (ph > 0) & (ph < 31) & (pw > 0) & (pw < 31);
    if (kk == 11)      filt_spec<11>(xb, h, w, nix, niy, nir, ib, out, id);
    else if (kk == 9)  filt_spec<9>(xb, h, w, nix, niy, nir, ib, out, id);
    else if (kk == 13) filt_spec<13>(xb, h, w, nix, niy, nir, ib, out, id);
    else if (kk == 7)  filt_spec<7>(xb, h, w, nix, niy, nir, ib, out, id);
    else               filt_generic(xb, h, w, kk, nix, niy, nir, out, id);
}

extern "C" void kernel_launch(void* const* d_in, const int* in_sizes, int n_in,
                              void* d_out, int out_size, void* d_ws, size_t ws_size,
                              hipStream_t stream) {
    const float* x    = (const float*)d_in[0];
    const float* Wq   = (const float*)d_in[1];
    const float* bq   = (const float*)d_in[2];
    const float* Wk   = (const float*)d_in[3];
    const float* bk   = (const float*)d_in[4];
    const float* Wv   = (const float*)d_in[5];
    const float* bv   = (const float*)d_in[6];
    const float* Wsq  = (const float*)d_in[7];
    const float* bsq  = (const float*)d_in[8];
    const float* Wsk  = (const float*)d_in[9];
    const float* bsk  = (const float*)d_in[10];
    const float* Wsv  = (const float*)d_in[11];
    const float* bsv  = (const float*)d_in[12];
    const float* ln_g = (const float*)d_in[13];
    const float* ln_b = (const float*)d_in[14];
    const float* Wp   = (const float*)d_in[15];
    const float* bp   = (const float*)d_in[16];
    float* out = (float*)d_out;

    float* ws = (float*)d_ws;
    float* Q   = ws;                 // 16384 floats
    float* Kf  = ws + 16384;
    float* Vf  = ws + 32768;
    float* SQ  = ws + 49152;
    float* SK  = ws + 65536;
    float* SV  = ws + 81920;
    float* SP  = ws + 98304;         // 6144 floats
    unsigned int* maxbits = (unsigned int*)(ws + 104448);

    qkv_kernel<<<B * N, 256, 0, stream>>>(x, Wq, bq, Wk, bk, Wv, bv, Q, Kf, Vf, maxbits);
    attn_proj_kernel<<<B * N / 8, 256, 0, stream>>>(Q, Kf, Vf, Wsq, bsq, Wsk, bsk, Wsv, bsv, SQ, SK, SV);
    attn_head_kernel<<<B * N / 8, 256, 0, stream>>>(SQ, SK, SV, ln_g, ln_b, Wp, bp, SP, maxbits);
    filter_kernel<<<B * N, 256, 0, stream>>>(x, SP, maxbits, out);
}